// Round 1
// 615.480 us; speedup vs baseline: 1.1275x; 1.1275x over previous
//
#include <hip/hip_runtime.h>
#include <cfloat>

#define NROWS 131072
#define DIM 256
#define KCODES 512
#define DECAYF 0.99f
#define OMDECAYF 0.01f
#define EPSF 1e-5f
#define BATCHF 32.0f

#define CHUNK 128
#define ROWMASK 0x1FFFF
#define GBLOCKS 1024

// ---- MFMA argmin geometry ----
#define PC 32                 // codes staged per LDS piece
#define NPIECE (KCODES / PC)  // 16
#define RT 2                  // row-tiles (16 rows each) per wave
#define BMW (RT * 16)         // 32 rows per wave
#define BMB (4 * BMW)         // 128 rows per block (4 waves)

typedef __attribute__((ext_vector_type(8))) short short8;  // 8 bf16 = 4 VGPR
typedef __attribute__((ext_vector_type(4))) float f32x4;

// ---------------- ws layout (bytes) ----------------
// 0      : cnorm       512 f
// 2048   : counts      512 i   (memset 0 each launch)
// 6144   : cursor      512 i   (written by scan)
// 8192   : loss_part   1024 f  (written by gather, reduced in scan)
// 12288  : enc_int     131072 i
// 536576 : rowlist     131072 i  (packed (code<<17)|row, sorted by code)
// bf16 codebook planes (786 KB) live in the out_code region of d_out:
// written by cnorm_kernel, consumed by argmin_kernel, then overwritten by gather.

__device__ __forceinline__ unsigned short f2bf_rn(float f) {
  unsigned u = __float_as_uint(f);
  u += 0x7fffu + ((u >> 16) & 1u);   // round-to-nearest-even
  return (unsigned short)(u >> 16);
}
__device__ __forceinline__ float bf2f(unsigned short b) {
  return __uint_as_float(((unsigned)b) << 16);
}

// cnorm + init e_new output with decay*e_i + emit 3-way bf16 split planes of cb.
// v = h + m + l + r, |r| <= 2^-27 |v|  (each split is RNE, residuals exact in f32)
__global__ __launch_bounds__(256) void cnorm_kernel(const float* __restrict__ cb,
                                                    const float* __restrict__ e_i,
                                                    float* __restrict__ cnorm,
                                                    float* __restrict__ en_out,
                                                    unsigned short* __restrict__ planes) {
  int k = blockIdx.x;
  int t = threadIdx.x;
  size_t idx = (size_t)k * DIM + t;
  float v = cb[idx];
  en_out[idx] = DECAYF * e_i[idx];
  unsigned short h = f2bf_rn(v);
  float r1 = v - bf2f(h);         // exact
  unsigned short m = f2bf_rn(r1);
  float r2 = r1 - bf2f(m);        // exact
  unsigned short l = f2bf_rn(r2);
  planes[idx] = h;                                  // plane h: [512][256]
  planes[(size_t)KCODES * DIM + idx] = m;           // plane m
  planes[(size_t)2 * KCODES * DIM + idx] = l;       // plane l
  float s = v * v;
  for (int off = 32; off > 0; off >>= 1) s += __shfl_down(s, off);
  __shared__ float p[4];
  if ((t & 63) == 0) p[t >> 6] = s;
  __syncthreads();
  if (t == 0) cnorm[k] = (p[0] + p[1]) + (p[2] + p[3]);
}

// MFMA distance-GEMM + argmin + histogram.
// score = ||c||^2 - 2*dot (||z||^2 constant per row). dot via 6 bf16 MFMA
// products of the 3-way splits: hh + hm + mh + hl + lh + mm  (error ~2^-27 scale,
// far below the fp32 reference's own rounding noise -> argmin decisions safe).
// Block: 256 thr = 4 waves; wave holds 32 z-rows (2 row-tiles) x 256 dims x 3
// splits in registers; codebook staged per 32-code piece in swizzled LDS.
__global__ __launch_bounds__(256, 2) void argmin_kernel(
    const float* __restrict__ z, const unsigned short* __restrict__ planes,
    const float* __restrict__ cnorm, int* __restrict__ enc_int,
    float* __restrict__ enc_out, int* __restrict__ counts) {
  __shared__ __align__(16) unsigned char sbuf[PC * DIM * 3 * 2];  // 48 KiB
  __shared__ float cn_s[KCODES];
  __shared__ int hist[KCODES];

  const int tid = threadIdx.x;
  const int w = tid >> 6;
  const int l = tid & 63;
  const int lc = l & 15;   // fragment row/col index
  const int lk = l >> 4;   // k-group (0..3)

  hist[tid] = 0;
  hist[tid + 256] = 0;
  cn_s[tid] = cnorm[tid];
  cn_s[tid + 256] = cnorm[tid + 256];

  // ---- load this wave's 32 z-rows into register fragments (3 bf16 splits) ----
  // A-frag layout for mfma_f32_16x16x32_bf16: lane holds row (l&15),
  // k = (l>>4)*8 + j, j=0..7 contiguous.
  short8 a_h[RT][8], a_m[RT][8], a_l[RT][8];
#pragma unroll
  for (int rt = 0; rt < RT; ++rt) {
    int row = blockIdx.x * BMB + w * BMW + rt * 16 + lc;
    const float* zr = z + (size_t)row * DIM;
#pragma unroll
    for (int ch = 0; ch < 8; ++ch) {
      float4 v0 = *(const float4*)&zr[ch * 32 + lk * 8];
      float4 v1 = *(const float4*)&zr[ch * 32 + lk * 8 + 4];
      float vv[8] = {v0.x, v0.y, v0.z, v0.w, v1.x, v1.y, v1.z, v1.w};
      short8 hh, mm, ll;
#pragma unroll
      for (int j = 0; j < 8; ++j) {
        float f = vv[j];
        unsigned short hb = f2bf_rn(f);
        float r1 = f - bf2f(hb);
        unsigned short mb = f2bf_rn(r1);
        float r2 = r1 - bf2f(mb);
        unsigned short lb = f2bf_rn(r2);
        hh[j] = (short)hb; mm[j] = (short)mb; ll[j] = (short)lb;
      }
      a_h[rt][ch] = hh; a_m[rt][ch] = mm; a_l[rt][ch] = ll;
    }
  }

  float minv[RT][4];
  int mini[RT][4];
#pragma unroll
  for (int rt = 0; rt < RT; ++rt)
#pragma unroll
    for (int q = 0; q < 4; ++q) { minv[rt][q] = FLT_MAX; mini[rt][q] = 0; }

#pragma unroll 1
  for (int pc = 0; pc < NPIECE; ++pc) {
    __syncthreads();
    // ---- stage piece pc: 3 planes x 32 codes x 256 dims bf16 = 3072 x 16B ----
    // LDS XOR-swizzle: byte ^= ((code&7)<<4) so code-major b128 fragment reads
    // spread over all 8 bank-quads (unswizzled stride-512B would serialize 2x).
#pragma unroll 1
    for (int batch = 0; batch < 3; ++batch) {
      float4 tmp[4];
      int so[4];
#pragma unroll
      for (int i = 0; i < 4; ++i) {
        int b = (batch * 4 + i) * 256 + tid;   // 16B-block index in piece
        int p = b >> 10;                       // plane
        int wb = b & 1023;                     // block within plane-slab
        tmp[i] = *((const float4*)(planes + (size_t)p * KCODES * DIM +
                                   (size_t)pc * PC * DIM) + wb);
        int o = b << 4;
        so[i] = o ^ (((o >> 9) & 7) << 4);
      }
#pragma unroll
      for (int i = 0; i < 4; ++i) *(float4*)&sbuf[so[i]] = tmp[i];
    }
    __syncthreads();

    // ---- compute: 2 code-tiles of 16 ----
#pragma unroll
    for (int ct = 0; ct < 2; ++ct) {
      const int ci = ct * 16 + lc;
      const int xo = (ci & 7) << 4;
      const int ebase = (ci << 9) + (lk << 4);
      f32x4 acc0 = {0.f, 0.f, 0.f, 0.f};
      f32x4 acc1 = {0.f, 0.f, 0.f, 0.f};
#pragma unroll
      for (int kc = 0; kc < 8; ++kc) {
        int e = ebase + kc * 64;
        short8 bh = *(const short8*)&sbuf[(e) ^ xo];
        short8 bm = *(const short8*)&sbuf[(e + PC * DIM * 2) ^ xo];
        short8 bl = *(const short8*)&sbuf[(e + 2 * PC * DIM * 2) ^ xo];
        acc0 = __builtin_amdgcn_mfma_f32_16x16x32_bf16(a_h[0][kc], bh, acc0, 0, 0, 0);
        acc1 = __builtin_amdgcn_mfma_f32_16x16x32_bf16(a_h[1][kc], bh, acc1, 0, 0, 0);
        acc0 = __builtin_amdgcn_mfma_f32_16x16x32_bf16(a_m[0][kc], bh, acc0, 0, 0, 0);
        acc1 = __builtin_amdgcn_mfma_f32_16x16x32_bf16(a_m[1][kc], bh, acc1, 0, 0, 0);
        acc0 = __builtin_amdgcn_mfma_f32_16x16x32_bf16(a_l[0][kc], bh, acc0, 0, 0, 0);
        acc1 = __builtin_amdgcn_mfma_f32_16x16x32_bf16(a_l[1][kc], bh, acc1, 0, 0, 0);
        acc0 = __builtin_amdgcn_mfma_f32_16x16x32_bf16(a_h[0][kc], bm, acc0, 0, 0, 0);
        acc1 = __builtin_amdgcn_mfma_f32_16x16x32_bf16(a_h[1][kc], bm, acc1, 0, 0, 0);
        acc0 = __builtin_amdgcn_mfma_f32_16x16x32_bf16(a_m[0][kc], bm, acc0, 0, 0, 0);
        acc1 = __builtin_amdgcn_mfma_f32_16x16x32_bf16(a_m[1][kc], bm, acc1, 0, 0, 0);
        acc0 = __builtin_amdgcn_mfma_f32_16x16x32_bf16(a_h[0][kc], bl, acc0, 0, 0, 0);
        acc1 = __builtin_amdgcn_mfma_f32_16x16x32_bf16(a_h[1][kc], bl, acc1, 0, 0, 0);
      }
      // C layout: col = lane&15 (code), row = (lane>>4)*4 + q
      int code = pc * PC + ci;
      float cn = cn_s[code];
#pragma unroll
      for (int q = 0; q < 4; ++q) {
        float s0 = cn - 2.f * acc0[q];
        if (s0 < minv[0][q]) { minv[0][q] = s0; mini[0][q] = code; }
        float s1 = cn - 2.f * acc1[q];
        if (s1 < minv[1][q]) { minv[1][q] = s1; mini[1][q] = code; }
      }
    }
  }

  // ---- cross-lane argmin over the 16 code-lanes of each row group ----
#pragma unroll
  for (int rt = 0; rt < RT; ++rt) {
#pragma unroll
    for (int q = 0; q < 4; ++q) {
      float v = minv[rt][q];
      int idx = mini[rt][q];
      for (int off = 1; off < 16; off <<= 1) {
        float ov = __shfl_xor(v, off);
        int oi = __shfl_xor(idx, off);
        if (ov < v || (ov == v && oi < idx)) { v = ov; idx = oi; }  // first-min wins
      }
      if (lc == 0) {
        int row = blockIdx.x * BMB + w * BMW + rt * 16 + lk * 4 + q;
        enc_int[row] = idx;
        enc_out[row] = (float)idx;
        atomicAdd(&hist[idx], 1);
      }
    }
  }
  __syncthreads();
  atomicAdd(&counts[tid], hist[tid]);
  atomicAdd(&counts[tid + 256], hist[tid + 256]);
}

// code gather -> code_ste output, per-block loss partials (NO same-address atomics)
__global__ __launch_bounds__(256) void gather_kernel(
    const float* __restrict__ z, const float* __restrict__ cb,
    const int* __restrict__ enc, float* __restrict__ code_out,
    float* __restrict__ loss_part) {
  const int per_block = (NROWS * (DIM / 4)) / GBLOCKS;  // 8192 float4s
  int base = blockIdx.x * per_block;
  float s = 0.f;
  for (int it = 0; it < per_block; it += 256) {
    int e4 = base + it + threadIdx.x;
    int row = e4 >> 6;        // 64 float4 per row
    int d4 = (e4 & 63) << 2;
    int k = enc[row];
    float4 zv = *(const float4*)&z[(size_t)e4 * 4];
    float4 cv = *(const float4*)&cb[(size_t)k * DIM + d4];
    *(float4*)&code_out[(size_t)e4 * 4] = cv;
    float dx = zv.x - cv.x, dy = zv.y - cv.y, dz = zv.z - cv.z, dw = zv.w - cv.w;
    s += dx * dx + dy * dy + dz * dz + dw * dw;
  }
  for (int off = 32; off > 0; off >>= 1) s += __shfl_down(s, off);
  __shared__ float p[4];
  int t = threadIdx.x;
  if ((t & 63) == 0) p[t >> 6] = s;
  __syncthreads();
  if (t == 0) loss_part[blockIdx.x] = (p[0] + p[1]) + (p[2] + p[3]);
}

// single block: n_new + exclusive prefix sum of counts -> cursor; loss reduce
__global__ __launch_bounds__(512) void scan_kernel(
    const int* __restrict__ counts, const float* __restrict__ n_i,
    float* __restrict__ n_new_out, int* __restrict__ cursor,
    const float* __restrict__ loss_part, float* __restrict__ loss_out) {
  __shared__ int sd[KCODES];
  int t = threadIdx.x;
  int c = counts[t];
  float nn = DECAYF * n_i[t] + OMDECAYF * (float)c;
  nn = (nn + EPSF) / (BATCHF + (float)KCODES * EPSF) * BATCHF;
  n_new_out[t] = nn;
  sd[t] = c;
  __syncthreads();
  for (int off = 1; off < KCODES; off <<= 1) {
    int v = (t >= off) ? sd[t - off] : 0;
    __syncthreads();
    sd[t] += v;
    __syncthreads();
  }
  cursor[t] = sd[t] - c;
  // loss reduction: 1024 partials over 512 threads
  float ls = loss_part[t] + loss_part[t + 512];
  for (int off = 32; off > 0; off >>= 1) ls += __shfl_down(ls, off);
  __shared__ float lp[8];
  if ((t & 63) == 0) lp[t >> 6] = ls;
  __syncthreads();
  if (t == 0) {
    float tot = 0.f;
#pragma unroll
    for (int i = 0; i < 8; ++i) tot += lp[i];
    loss_out[0] = 0.25f * tot / 33554432.0f;
  }
}

// LDS-aggregated counting-sort scatter: writes packed (code<<17)|row.
__global__ __launch_bounds__(256) void scatter_kernel(
    const int* __restrict__ enc, int* __restrict__ cursor,
    int* __restrict__ rowlist) {
  __shared__ int lcnt[KCODES];
  __shared__ int lbase[KCODES];
  int tid = threadIdx.x;
  int row = blockIdx.x * 256 + tid;
  lcnt[tid] = 0;
  lcnt[tid + 256] = 0;
  __syncthreads();
  int k = enc[row];
  int p = atomicAdd(&lcnt[k], 1);
  __syncthreads();
  int c0 = lcnt[tid];
  if (c0) lbase[tid] = atomicAdd(&cursor[tid], c0);
  int c1 = lcnt[tid + 256];
  if (c1) lbase[tid + 256] = atomicAdd(&cursor[tid + 256], c1);
  __syncthreads();
  rowlist[lbase[k] + p] = (k << 17) | row;
}

// Load-balanced segmented sum over sorted rowlist: 128 rows per block,
// run-length accumulate in registers, one atomicAdd per run per dim.
__global__ __launch_bounds__(256) void chunk_sum_kernel(
    const float* __restrict__ z, const int* __restrict__ rowlist,
    float* __restrict__ en_out) {
  __shared__ int rl[CHUNK];
  int tid = threadIdx.x;
  int d = tid;
  if (tid < CHUNK) rl[tid] = rowlist[blockIdx.x * CHUNK + tid];
  __syncthreads();
  int cur = rl[0] >> 17;
  float s = 0.f;
  for (int i = 0; i < CHUNK; i += 4) {
    int p0 = rl[i + 0], p1 = rl[i + 1], p2 = rl[i + 2], p3 = rl[i + 3];
    float v0 = z[(size_t)(p0 & ROWMASK) * DIM + d];
    float v1 = z[(size_t)(p1 & ROWMASK) * DIM + d];
    float v2 = z[(size_t)(p2 & ROWMASK) * DIM + d];
    float v3 = z[(size_t)(p3 & ROWMASK) * DIM + d];
    int k;
    k = p0 >> 17;
    if (k != cur) { atomicAdd(&en_out[(size_t)cur * DIM + d], OMDECAYF * s); s = 0.f; cur = k; }
    s += v0;
    k = p1 >> 17;
    if (k != cur) { atomicAdd(&en_out[(size_t)cur * DIM + d], OMDECAYF * s); s = 0.f; cur = k; }
    s += v1;
    k = p2 >> 17;
    if (k != cur) { atomicAdd(&en_out[(size_t)cur * DIM + d], OMDECAYF * s); s = 0.f; cur = k; }
    s += v2;
    k = p3 >> 17;
    if (k != cur) { atomicAdd(&en_out[(size_t)cur * DIM + d], OMDECAYF * s); s = 0.f; cur = k; }
    s += v3;
  }
  atomicAdd(&en_out[(size_t)cur * DIM + d], OMDECAYF * s);
}

// cbn = e_new / n_new
__global__ __launch_bounds__(256) void finalize_kernel(
    const float* __restrict__ en, const float* __restrict__ n_new,
    float* __restrict__ cbn_out) {
  int k = blockIdx.x;
  int d = threadIdx.x;
  size_t idx = (size_t)k * DIM + d;
  cbn_out[idx] = en[idx] / n_new[k];
}

extern "C" void kernel_launch(void* const* d_in, const int* in_sizes, int n_in,
                              void* d_out, int out_size, void* d_ws, size_t ws_size,
                              hipStream_t stream) {
  const float* z = (const float*)d_in[0];
  const float* cb = (const float*)d_in[1];
  const float* n_i = (const float*)d_in[2];
  const float* e_i = (const float*)d_in[3];

  float* out = (float*)d_out;
  float* out_code = out;                    // 33554432
  float* out_loss = out + 33554432;         // 1
  float* out_enc = out + 33554433;          // 131072
  float* out_cbn = out + 33685505;          // 131072
  float* out_nn = out + 33816577;           // 512
  float* out_en = out + 33817089;           // 131072

  char* ws = (char*)d_ws;
  float* cnorm = (float*)(ws + 0);
  int* counts = (int*)(ws + 2048);
  int* cursor = (int*)(ws + 6144);
  float* loss_part = (float*)(ws + 8192);
  int* enc_int = (int*)(ws + 12288);
  int* rowlist = (int*)(ws + 536576);

  // bf16 split planes of the codebook: scratch inside out_code (786 KB),
  // consumed by argmin before gather overwrites the region (stream-ordered).
  unsigned short* planes = (unsigned short*)out_code;

  // zero counts (ws is poisoned 0xAA before each launch)
  hipMemsetAsync(ws + 2048, 0, 2048, stream);

  cnorm_kernel<<<KCODES, 256, 0, stream>>>(cb, e_i, cnorm, out_en, planes);
  argmin_kernel<<<NROWS / BMB, 256, 0, stream>>>(z, planes, cnorm, enc_int, out_enc, counts);
  gather_kernel<<<GBLOCKS, 256, 0, stream>>>(z, cb, enc_int, out_code, loss_part);
  scan_kernel<<<1, KCODES, 0, stream>>>(counts, n_i, out_nn, cursor, loss_part, out_loss);
  scatter_kernel<<<NROWS / 256, 256, 0, stream>>>(enc_int, cursor, rowlist);
  chunk_sum_kernel<<<NROWS / CHUNK, 256, 0, stream>>>(z, rowlist, out_en);
  finalize_kernel<<<KCODES, 256, 0, stream>>>(out_en, out_nn, out_cbn);
}

// Round 2
// 404.415 us; speedup vs baseline: 1.7160x; 1.5219x over previous
//
#include <hip/hip_runtime.h>
#include <cfloat>

#define NROWS 131072
#define DIM 256
#define KCODES 512
#define DECAYF 0.99f
#define OMDECAYF 0.01f
#define EPSF 1e-5f
#define BATCHF 32.0f

#define CHUNK 128
#define ROWMASK 0x1FFFF
#define GBLOCKS 1024

// ---- MFMA argmin geometry ----
#define PC 32                 // codes staged per LDS piece
#define NPIECE (KCODES / PC)  // 16
#define RT 2                  // row-tiles (16 rows each) per wave
#define BMW (RT * 16)         // 32 rows per wave
#define BMB (4 * BMW)         // 128 rows per block (4 waves)
#define PLANE_STRIDE (KCODES * DIM)   // halves per cb plane

typedef __attribute__((ext_vector_type(8))) _Float16 half8;  // 8 f16 = 4 VGPR
typedef __attribute__((ext_vector_type(4))) float f32x4;

// ---------------- ws layout (bytes) ----------------
// 0      : cnorm       512 f
// 2048   : counts      512 i   (memset 0 each launch)
// 6144   : cursor      512 i   (written by scan)
// 8192   : loss_part   1024 f  (written by gather, reduced in scan)
// 12288  : enc_int     131072 i
// 536576 : rowlist     131072 i  (packed (code<<17)|row, sorted by code)
// fp16 codebook planes (512 KB) live in the out_code region of d_out:
// written by cnorm_kernel, consumed by argmin_kernel, then overwritten by gather.

// cnorm + init e_new output with decay*e_i + emit 2-way fp16 split planes of cb.
// v = h + m + r with h=RNE_f16(v), m=RNE_f16(v-h); |r| <= 2^-22 |v|.
// 4 MFMA products (hh,hm,mh,mm) then capture (h+m)(H+M) exactly in fp32 acc;
// dropped residual terms ~2^-22 -> dot error ~2e-6, far below the fp32
// reference's own summation-order noise (~3e-5) that already passed with
// zero encoding flips -> argmin decisions safe.
__global__ __launch_bounds__(256) void cnorm_kernel(const float* __restrict__ cb,
                                                    const float* __restrict__ e_i,
                                                    float* __restrict__ cnorm,
                                                    float* __restrict__ en_out,
                                                    unsigned short* __restrict__ planes) {
  int k = blockIdx.x;
  int t = threadIdx.x;
  size_t idx = (size_t)k * DIM + t;
  float v = cb[idx];
  en_out[idx] = DECAYF * e_i[idx];
  _Float16 h = (_Float16)v;           // RNE
  float r1 = v - (float)h;            // exact
  _Float16 m = (_Float16)r1;          // RNE
  unsigned short hb, mb;
  __builtin_memcpy(&hb, &h, 2);
  __builtin_memcpy(&mb, &m, 2);
  planes[idx] = hb;                   // plane h: [512][256]
  planes[PLANE_STRIDE + idx] = mb;    // plane m
  float s = v * v;
  for (int off = 32; off > 0; off >>= 1) s += __shfl_down(s, off);
  __shared__ float p[4];
  if ((t & 63) == 0) p[t >> 6] = s;
  __syncthreads();
  if (t == 0) cnorm[k] = (p[0] + p[1]) + (p[2] + p[3]);
}

// MFMA distance-GEMM + argmin + histogram.
// score = ||c||^2 - 2*dot (||z||^2 constant per row). dot via 4 f16 MFMA
// products of the 2-way splits. Block: 256 thr = 4 waves; wave holds 32
// z-rows (2 row-tiles) x 256 dims x 2 splits in regs = 128 VGPRs of
// fragments (total pressure ~195 < 256 cap -> NO spill; round-1's 3-split
// version needed 192 frag VGPRs, spilled 768B/thread = the 216MB WRITE_SIZE).
__global__ __launch_bounds__(256, 2) void argmin_kernel(
    const float* __restrict__ z, const unsigned short* __restrict__ planes,
    const float* __restrict__ cnorm, int* __restrict__ enc_int,
    float* __restrict__ enc_out, int* __restrict__ counts) {
  __shared__ __align__(16) unsigned char sbuf[PC * DIM * 2 * 2];  // 32 KiB
  __shared__ float cn_s[KCODES];
  __shared__ int hist[KCODES];

  const int tid = threadIdx.x;
  const int w = tid >> 6;
  const int l = tid & 63;
  const int lc = l & 15;   // fragment row/col index
  const int lk = l >> 4;   // k-group (0..3)

  hist[tid] = 0;
  hist[tid + 256] = 0;
  cn_s[tid] = cnorm[tid];
  cn_s[tid + 256] = cnorm[tid + 256];

  // ---- load this wave's 32 z-rows into register fragments (2 fp16 splits) ----
  // A-frag layout for mfma_f32_16x16x32_f16: lane holds row (l&15),
  // k = (l>>4)*8 + j, j=0..7 contiguous.
  half8 a_h[RT][8], a_m[RT][8];
#pragma unroll
  for (int rt = 0; rt < RT; ++rt) {
    int row = blockIdx.x * BMB + w * BMW + rt * 16 + lc;
    const float* zr = z + (size_t)row * DIM;
#pragma unroll
    for (int ch = 0; ch < 8; ++ch) {
      float4 v0 = *(const float4*)&zr[ch * 32 + lk * 8];
      float4 v1 = *(const float4*)&zr[ch * 32 + lk * 8 + 4];
      float vv[8] = {v0.x, v0.y, v0.z, v0.w, v1.x, v1.y, v1.z, v1.w};
      half8 hh, mm;
#pragma unroll
      for (int j = 0; j < 8; ++j) {
        float f = vv[j];
        _Float16 hb = (_Float16)f;     // RNE
        float r1 = f - (float)hb;      // exact
        hh[j] = hb;
        mm[j] = (_Float16)r1;          // RNE
      }
      a_h[rt][ch] = hh; a_m[rt][ch] = mm;
    }
  }

  float minv[RT][4];
  int mini[RT][4];
#pragma unroll
  for (int rt = 0; rt < RT; ++rt)
#pragma unroll
    for (int q = 0; q < 4; ++q) { minv[rt][q] = FLT_MAX; mini[rt][q] = 0; }

#pragma unroll 1
  for (int pc = 0; pc < NPIECE; ++pc) {
    __syncthreads();
    // ---- stage piece pc: 2 planes x 32 codes x 256 dims f16 = 2048 x 16B ----
    // LDS XOR-swizzle: byte ^= ((code&7)<<4) so code-major b128 fragment reads
    // spread over all 8 bank-quads (unswizzled stride-512B would serialize).
#pragma unroll 1
    for (int batch = 0; batch < 2; ++batch) {
      float4 tmp[4];
      int so[4];
#pragma unroll
      for (int i = 0; i < 4; ++i) {
        int b = (batch * 4 + i) * 256 + tid;   // 16B-block index in piece
        int p = b >> 10;                       // plane (1024 blocks per plane)
        int wb = b & 1023;                     // block within plane-slab
        tmp[i] = *((const float4*)(planes + (size_t)p * PLANE_STRIDE +
                                   (size_t)pc * PC * DIM) + wb);
        int o = b << 4;
        so[i] = o ^ (((o >> 9) & 7) << 4);
      }
#pragma unroll
      for (int i = 0; i < 4; ++i) *(float4*)&sbuf[so[i]] = tmp[i];
    }
    __syncthreads();

    // ---- compute: 2 code-tiles of 16 ----
#pragma unroll
    for (int ct = 0; ct < 2; ++ct) {
      const int ci = ct * 16 + lc;
      const int xo = (ci & 7) << 4;
      const int ebase = (ci << 9) + (lk << 4);
      f32x4 acc0 = {0.f, 0.f, 0.f, 0.f};
      f32x4 acc1 = {0.f, 0.f, 0.f, 0.f};
#pragma unroll
      for (int kc = 0; kc < 8; ++kc) {
        int e = ebase + kc * 64;
        half8 bh = *(const half8*)&sbuf[(e) ^ xo];
        half8 bm = *(const half8*)&sbuf[(e + PC * DIM * 2) ^ xo];
        acc0 = __builtin_amdgcn_mfma_f32_16x16x32_f16(a_h[0][kc], bh, acc0, 0, 0, 0);
        acc1 = __builtin_amdgcn_mfma_f32_16x16x32_f16(a_h[1][kc], bh, acc1, 0, 0, 0);
        acc0 = __builtin_amdgcn_mfma_f32_16x16x32_f16(a_m[0][kc], bh, acc0, 0, 0, 0);
        acc1 = __builtin_amdgcn_mfma_f32_16x16x32_f16(a_m[1][kc], bh, acc1, 0, 0, 0);
        acc0 = __builtin_amdgcn_mfma_f32_16x16x32_f16(a_h[0][kc], bm, acc0, 0, 0, 0);
        acc1 = __builtin_amdgcn_mfma_f32_16x16x32_f16(a_h[1][kc], bm, acc1, 0, 0, 0);
        acc0 = __builtin_amdgcn_mfma_f32_16x16x32_f16(a_m[0][kc], bm, acc0, 0, 0, 0);
        acc1 = __builtin_amdgcn_mfma_f32_16x16x32_f16(a_m[1][kc], bm, acc1, 0, 0, 0);
      }
      // C layout: col = lane&15 (code), row = (lane>>4)*4 + q
      int code = pc * PC + ci;
      float cn = cn_s[code];
#pragma unroll
      for (int q = 0; q < 4; ++q) {
        float s0 = cn - 2.f * acc0[q];
        if (s0 < minv[0][q]) { minv[0][q] = s0; mini[0][q] = code; }
        float s1 = cn - 2.f * acc1[q];
        if (s1 < minv[1][q]) { minv[1][q] = s1; mini[1][q] = code; }
      }
    }
  }

  // ---- cross-lane argmin over the 16 code-lanes of each row group ----
#pragma unroll
  for (int rt = 0; rt < RT; ++rt) {
#pragma unroll
    for (int q = 0; q < 4; ++q) {
      float v = minv[rt][q];
      int idx = mini[rt][q];
      for (int off = 1; off < 16; off <<= 1) {
        float ov = __shfl_xor(v, off);
        int oi = __shfl_xor(idx, off);
        if (ov < v || (ov == v && oi < idx)) { v = ov; idx = oi; }  // first-min wins
      }
      if (lc == 0) {
        int row = blockIdx.x * BMB + w * BMW + rt * 16 + lk * 4 + q;
        enc_int[row] = idx;
        enc_out[row] = (float)idx;
        atomicAdd(&hist[idx], 1);
      }
    }
  }
  __syncthreads();
  atomicAdd(&counts[tid], hist[tid]);
  atomicAdd(&counts[tid + 256], hist[tid + 256]);
}

// code gather -> code_ste output, per-block loss partials (NO same-address atomics)
__global__ __launch_bounds__(256) void gather_kernel(
    const float* __restrict__ z, const float* __restrict__ cb,
    const int* __restrict__ enc, float* __restrict__ code_out,
    float* __restrict__ loss_part) {
  const int per_block = (NROWS * (DIM / 4)) / GBLOCKS;  // 8192 float4s
  int base = blockIdx.x * per_block;
  float s = 0.f;
  for (int it = 0; it < per_block; it += 256) {
    int e4 = base + it + threadIdx.x;
    int row = e4 >> 6;        // 64 float4 per row
    int d4 = (e4 & 63) << 2;
    int k = enc[row];
    float4 zv = *(const float4*)&z[(size_t)e4 * 4];
    float4 cv = *(const float4*)&cb[(size_t)k * DIM + d4];
    *(float4*)&code_out[(size_t)e4 * 4] = cv;
    float dx = zv.x - cv.x, dy = zv.y - cv.y, dz = zv.z - cv.z, dw = zv.w - cv.w;
    s += dx * dx + dy * dy + dz * dz + dw * dw;
  }
  for (int off = 32; off > 0; off >>= 1) s += __shfl_down(s, off);
  __shared__ float p[4];
  int t = threadIdx.x;
  if ((t & 63) == 0) p[t >> 6] = s;
  __syncthreads();
  if (t == 0) loss_part[blockIdx.x] = (p[0] + p[1]) + (p[2] + p[3]);
}

// single block: n_new + exclusive prefix sum of counts -> cursor; loss reduce
__global__ __launch_bounds__(512) void scan_kernel(
    const int* __restrict__ counts, const float* __restrict__ n_i,
    float* __restrict__ n_new_out, int* __restrict__ cursor,
    const float* __restrict__ loss_part, float* __restrict__ loss_out) {
  __shared__ int sd[KCODES];
  int t = threadIdx.x;
  int c = counts[t];
  float nn = DECAYF * n_i[t] + OMDECAYF * (float)c;
  nn = (nn + EPSF) / (BATCHF + (float)KCODES * EPSF) * BATCHF;
  n_new_out[t] = nn;
  sd[t] = c;
  __syncthreads();
  for (int off = 1; off < KCODES; off <<= 1) {
    int v = (t >= off) ? sd[t - off] : 0;
    __syncthreads();
    sd[t] += v;
    __syncthreads();
  }
  cursor[t] = sd[t] - c;
  // loss reduction: 1024 partials over 512 threads
  float ls = loss_part[t] + loss_part[t + 512];
  for (int off = 32; off > 0; off >>= 1) ls += __shfl_down(ls, off);
  __shared__ float lp[8];
  if ((t & 63) == 0) lp[t >> 6] = ls;
  __syncthreads();
  if (t == 0) {
    float tot = 0.f;
#pragma unroll
    for (int i = 0; i < 8; ++i) tot += lp[i];
    loss_out[0] = 0.25f * tot / 33554432.0f;
  }
}

// LDS-aggregated counting-sort scatter: writes packed (code<<17)|row.
__global__ __launch_bounds__(256) void scatter_kernel(
    const int* __restrict__ enc, int* __restrict__ cursor,
    int* __restrict__ rowlist) {
  __shared__ int lcnt[KCODES];
  __shared__ int lbase[KCODES];
  int tid = threadIdx.x;
  int row = blockIdx.x * 256 + tid;
  lcnt[tid] = 0;
  lcnt[tid + 256] = 0;
  __syncthreads();
  int k = enc[row];
  int p = atomicAdd(&lcnt[k], 1);
  __syncthreads();
  int c0 = lcnt[tid];
  if (c0) lbase[tid] = atomicAdd(&cursor[tid], c0);
  int c1 = lcnt[tid + 256];
  if (c1) lbase[tid + 256] = atomicAdd(&cursor[tid + 256], c1);
  __syncthreads();
  rowlist[lbase[k] + p] = (k << 17) | row;
}

// Load-balanced segmented sum over sorted rowlist: 128 rows per block,
// run-length accumulate in registers, one atomicAdd per run per dim.
__global__ __launch_bounds__(256) void chunk_sum_kernel(
    const float* __restrict__ z, const int* __restrict__ rowlist,
    float* __restrict__ en_out) {
  __shared__ int rl[CHUNK];
  int tid = threadIdx.x;
  int d = tid;
  if (tid < CHUNK) rl[tid] = rowlist[blockIdx.x * CHUNK + tid];
  __syncthreads();
  int cur = rl[0] >> 17;
  float s = 0.f;
  for (int i = 0; i < CHUNK; i += 4) {
    int p0 = rl[i + 0], p1 = rl[i + 1], p2 = rl[i + 2], p3 = rl[i + 3];
    float v0 = z[(size_t)(p0 & ROWMASK) * DIM + d];
    float v1 = z[(size_t)(p1 & ROWMASK) * DIM + d];
    float v2 = z[(size_t)(p2 & ROWMASK) * DIM + d];
    float v3 = z[(size_t)(p3 & ROWMASK) * DIM + d];
    int k;
    k = p0 >> 17;
    if (k != cur) { atomicAdd(&en_out[(size_t)cur * DIM + d], OMDECAYF * s); s = 0.f; cur = k; }
    s += v0;
    k = p1 >> 17;
    if (k != cur) { atomicAdd(&en_out[(size_t)cur * DIM + d], OMDECAYF * s); s = 0.f; cur = k; }
    s += v1;
    k = p2 >> 17;
    if (k != cur) { atomicAdd(&en_out[(size_t)cur * DIM + d], OMDECAYF * s); s = 0.f; cur = k; }
    s += v2;
    k = p3 >> 17;
    if (k != cur) { atomicAdd(&en_out[(size_t)cur * DIM + d], OMDECAYF * s); s = 0.f; cur = k; }
    s += v3;
  }
  atomicAdd(&en_out[(size_t)cur * DIM + d], OMDECAYF * s);
}

// cbn = e_new / n_new
__global__ __launch_bounds__(256) void finalize_kernel(
    const float* __restrict__ en, const float* __restrict__ n_new,
    float* __restrict__ cbn_out) {
  int k = blockIdx.x;
  int d = threadIdx.x;
  size_t idx = (size_t)k * DIM + d;
  cbn_out[idx] = en[idx] / n_new[k];
}

extern "C" void kernel_launch(void* const* d_in, const int* in_sizes, int n_in,
                              void* d_out, int out_size, void* d_ws, size_t ws_size,
                              hipStream_t stream) {
  const float* z = (const float*)d_in[0];
  const float* cb = (const float*)d_in[1];
  const float* n_i = (const float*)d_in[2];
  const float* e_i = (const float*)d_in[3];

  float* out = (float*)d_out;
  float* out_code = out;                    // 33554432
  float* out_loss = out + 33554432;         // 1
  float* out_enc = out + 33554433;          // 131072
  float* out_cbn = out + 33685505;          // 131072
  float* out_nn = out + 33816577;           // 512
  float* out_en = out + 33817089;           // 131072

  char* ws = (char*)d_ws;
  float* cnorm = (float*)(ws + 0);
  int* counts = (int*)(ws + 2048);
  int* cursor = (int*)(ws + 6144);
  float* loss_part = (float*)(ws + 8192);
  int* enc_int = (int*)(ws + 12288);
  int* rowlist = (int*)(ws + 536576);

  // fp16 split planes of the codebook: scratch inside out_code (512 KB),
  // consumed by argmin before gather overwrites the region (stream-ordered).
  unsigned short* planes = (unsigned short*)out_code;

  // zero counts (ws is poisoned 0xAA before each launch)
  hipMemsetAsync(ws + 2048, 0, 2048, stream);

  cnorm_kernel<<<KCODES, 256, 0, stream>>>(cb, e_i, cnorm, out_en, planes);
  argmin_kernel<<<NROWS / BMB, 256, 0, stream>>>(z, planes, cnorm, enc_int, out_enc, counts);
  gather_kernel<<<GBLOCKS, 256, 0, stream>>>(z, cb, enc_int, out_code, loss_part);
  scan_kernel<<<1, KCODES, 0, stream>>>(counts, n_i, out_nn, cursor, loss_part, out_loss);
  scatter_kernel<<<NROWS / 256, 256, 0, stream>>>(enc_int, cursor, rowlist);
  chunk_sum_kernel<<<NROWS / CHUNK, 256, 0, stream>>>(z, rowlist, out_en);
  finalize_kernel<<<KCODES, 256, 0, stream>>>(out_en, out_nn, out_cbn);
}